// Round 4
// baseline (285.705 us; speedup 1.0000x reference)
//
#include <hip/hip_runtime.h>
#include <cstdint>
#include <cstddef>

// x[B=32, T=4096, N=256] fp32 -> z same shape.
// Refractory scan: spike at step t iff x>0 and t >= na; then na = t+6.
// Entry state q==k  <=>  first k steps of chunk blocked (na=k). q in [0,5].
#define BB 32
#define TT 4096
#define NNV 64        // float4 groups per row (N=256)
#define CC 128        // chunk length (per-thread scan)
#define PSUB 4        // chunks handled per block (one per 64-thread group)
#define PG 8          // chunk-groups per chain: T / (CC*PSUB) = 8
#define MSG_STRIDE 64 // u32 per (b,pg) slot: [0..31]=data, [32]=flag, rest pad
#define READY_FLAG 0x0C0FFEE5u

__global__ __launch_bounds__(256) void refrac_fused(const float* __restrict__ x,
                                                    float* __restrict__ z,
                                                    uint32_t* __restrict__ msg) {
    const int tid = threadIdx.x;
    const int pg = blockIdx.x >> 5;   // chunk-group (time-major dispatch)
    const int b  = blockIdx.x & 31;   // batch
    const int psub = tid >> 6;        // which of the 4 chunks in this group
    const int n4 = tid & 63;          // float4 group along N
    const int p = pg * PSUB + psub;   // absolute chunk index

    const float4* __restrict__ xv = reinterpret_cast<const float4*>(x)
        + ((size_t)b * TT + (size_t)p * CC) * NNV + n4;

    // --- Phase 1: scan chunk for all 6 entry states; stash sign bits ---
    int na[4][6];
    #pragma unroll
    for (int c = 0; c < 4; ++c)
        #pragma unroll
        for (int e = 0; e < 6; ++e) na[c][e] = e;

    uint32_t bits[4][4];  // [chain][word], 128 bits per chain

    #pragma unroll
    for (int w = 0; w < 4; ++w) {
        uint32_t cur[4] = {0u, 0u, 0u, 0u};
        for (int jb = 0; jb < 32; jb += 8) {   // dynamic: keeps code size sane
            float4 buf[8];
            #pragma unroll
            for (int u = 0; u < 8; ++u)
                buf[u] = xv[(size_t)(w * 32 + jb + u) * NNV];
            #pragma unroll
            for (int u = 0; u < 8; ++u) {
                const int j2 = jb + u;         // bit position in word w
                const int j  = w * 32 + j2;    // step within chunk
                const float4 v = buf[u];
                const float fv[4] = {v.x, v.y, v.z, v.w};
                #pragma unroll
                for (int c = 0; c < 4; ++c) {
                    const bool pos = fv[c] > 0.0f;
                    cur[c] |= pos ? (1u << j2) : 0u;
                    #pragma unroll
                    for (int e = 0; e < 6; ++e)
                        if (pos & (j >= na[c][e])) na[c][e] = j + 6;
                }
            }
        }
        #pragma unroll
        for (int c = 0; c < 4; ++c) bits[c][w] = cur[c];
    }

    // Pack exit table (6 nibbles) per chain into LDS.
    __shared__ uint32_t tbl_lds[PSUB][256];
    __shared__ uint8_t  ent_lds[PSUB][256];
    __shared__ uint8_t  ent0_lds[256];   // entry state into this chunk-group
    __shared__ uint8_t  sout_lds[256];   // exit state out of this chunk-group

    #pragma unroll
    for (int c = 0; c < 4; ++c) {
        uint32_t tbl = 0;
        #pragma unroll
        for (int e = 0; e < 6; ++e) {
            int q = na[c][e] - CC;
            q = q > 0 ? q : 0;                 // exit state in [0,5]
            tbl |= (uint32_t)q << (4 * e);
        }
        tbl_lds[psub][n4 * 4 + c] = tbl;
    }

    // --- Phase 2a: single-lane flag poll (kills coherence-point contention) ---
    const size_t prev_base = ((size_t)b * PG + (pg - 1)) * MSG_STRIDE;
    if (pg > 0 && tid == 0) {
        while (__hip_atomic_load(msg + prev_base + 32, __ATOMIC_ACQUIRE,
                                 __HIP_MEMORY_SCOPE_AGENT) != READY_FLAG)
            __builtin_amdgcn_s_sleep(4);
    }
    __syncthreads();   // also publishes tbl_lds

    if (tid < 32) {
        uint32_t wv = 0;
        if (pg > 0)
            wv = __hip_atomic_load(msg + prev_base + tid, __ATOMIC_RELAXED,
                                   __HIP_MEMORY_SCOPE_AGENT);
        #pragma unroll
        for (int k = 0; k < 8; ++k)
            ent0_lds[tid * 8 + k] = (uint8_t)((wv >> (4 * k)) & 0xFu);
    }
    __syncthreads();

    // --- Phase 2b: compose entry states through the 4 chunk tables ---
    {
        const int n = tid;
        int e = (int)ent0_lds[n];
        #pragma unroll
        for (int s = 0; s < PSUB; ++s) {
            ent_lds[s][n] = (uint8_t)e;
            e = (int)((tbl_lds[s][n] >> (4 * e)) & 0xFu);
        }
        sout_lds[n] = (uint8_t)e;
    }
    __syncthreads();

    // --- Phase 2c: publish message (data words, barrier-drain, then flag) ---
    const size_t my_base = ((size_t)b * PG + pg) * MSG_STRIDE;
    if (pg < PG - 1) {
        if (tid < 32) {
            uint32_t wv = 0;
            #pragma unroll
            for (int k = 0; k < 8; ++k)
                wv |= (uint32_t)sout_lds[tid * 8 + k] << (4 * k);
            __hip_atomic_store(msg + my_base + tid, wv, __ATOMIC_RELAXED,
                               __HIP_MEMORY_SCOPE_AGENT);
        }
        __syncthreads();   // vmcnt(0): data words at coherence point
        if (tid == 0)
            __hip_atomic_store(msg + my_base + 32, READY_FLAG, __ATOMIC_RELEASE,
                               __HIP_MEMORY_SCOPE_AGENT);
    }

    // --- Phase 3: emit z from register bits + resolved entry ---
    float4* __restrict__ zv = reinterpret_cast<float4*>(z)
        + ((size_t)b * TT + (size_t)p * CC) * NNV + n4;

    int ea[4];
    #pragma unroll
    for (int c = 0; c < 4; ++c) ea[c] = (int)ent_lds[psub][n4 * 4 + c];

    #pragma unroll
    for (int w = 0; w < 4; ++w) {
        const uint32_t bw[4] = {bits[0][w], bits[1][w], bits[2][w], bits[3][w]};
        for (int j2 = 0; j2 < 32; ++j2) {
            const int j = w * 32 + j2;
            float o[4];
            #pragma unroll
            for (int c = 0; c < 4; ++c) {
                const bool sp = (((bw[c] >> j2) & 1u) != 0u) & (j >= ea[c]);
                if (sp) ea[c] = j + 6;
                o[c] = sp ? 1.0f : 0.0f;
            }
            zv[(size_t)j * NNV] = make_float4(o[0], o[1], o[2], o[3]);
        }
    }
}

extern "C" void kernel_launch(void* const* d_in, const int* in_sizes, int n_in,
                              void* d_out, int out_size, void* d_ws, size_t ws_size,
                              hipStream_t stream) {
    const float* x = (const float*)d_in[0];
    float* z = (float*)d_out;
    uint32_t* msg = (uint32_t*)d_ws;

    // Deterministic "not ready" state each call (0xAAAAAAAA != READY_FLAG).
    hipMemsetAsync(d_ws, 0xAA, (size_t)BB * PG * MSG_STRIDE * sizeof(uint32_t),
                   stream);

    refrac_fused<<<dim3(BB * PG), 256, 0, stream>>>(x, z, msg);
}

// Round 5
// 250.947 us; speedup vs baseline: 1.1385x; 1.1385x over previous
//
#include <hip/hip_runtime.h>
#include <cstdint>
#include <cstddef>

// x[B=32, T=4096, N=256] fp32 -> z same shape.
// Refractory scan: spike at step t iff x>0 and t >= na; then na = t+6.
// Entry state q==k  <=>  first k steps of chunk blocked (na=k). q in [0,5].
#define BB 32
#define TT 4096
#define NN 256
#define NNV 64        // float4 groups per row
#define CC 128        // chunk length (per-thread scan)
#define PSUB 4        // chunks per block (one per 64-thread group)
#define PP 32         // chunks per chain
#define PG 8          // chunk-groups (blocks per chain)

// ---------------- Kernel A: sign bits + 6-entry exit tables ----------------
__global__ __launch_bounds__(256) void refrac_scan(const float* __restrict__ x,
                                                   uint32_t* __restrict__ tbl,
                                                   uint32_t* __restrict__ bits_g) {
    const int tid = threadIdx.x;
    const int pg = blockIdx.x >> 5;
    const int b  = blockIdx.x & 31;
    const int psub = tid >> 6;
    const int n4 = tid & 63;
    const int p = pg * PSUB + psub;

    const float4* __restrict__ xv = reinterpret_cast<const float4*>(x)
        + ((size_t)b * TT + (size_t)p * CC) * NNV + n4;

    int na[4][6];
    #pragma unroll
    for (int c = 0; c < 4; ++c)
        #pragma unroll
        for (int e = 0; e < 6; ++e) na[c][e] = e;

    uint32_t bits[4][4];  // [chain][word]

    #pragma unroll
    for (int w = 0; w < 4; ++w) {
        uint32_t cur[4] = {0u, 0u, 0u, 0u};
        for (int jb = 0; jb < 32; jb += 8) {
            float4 buf[8];
            #pragma unroll
            for (int u = 0; u < 8; ++u)
                buf[u] = xv[(size_t)(w * 32 + jb + u) * NNV];
            #pragma unroll
            for (int u = 0; u < 8; ++u) {
                const int j2 = jb + u;
                const int j  = w * 32 + j2;
                const float4 v = buf[u];
                const float fv[4] = {v.x, v.y, v.z, v.w};
                #pragma unroll
                for (int c = 0; c < 4; ++c) {
                    const bool pos = fv[c] > 0.0f;
                    cur[c] |= pos ? (1u << j2) : 0u;
                    #pragma unroll
                    for (int e = 0; e < 6; ++e)
                        if (pos & (j >= na[c][e])) na[c][e] = j + 6;
                }
            }
        }
        #pragma unroll
        for (int c = 0; c < 4; ++c) bits[c][w] = cur[c];
    }

    const size_t row = (size_t)b * PP + p;

    // Exit table: 6 nibbles per chain, chains n=4*n4+c -> one uint4 store.
    uint32_t t4[4];
    #pragma unroll
    for (int c = 0; c < 4; ++c) {
        uint32_t t = 0;
        #pragma unroll
        for (int e = 0; e < 6; ++e) {
            int q = na[c][e] - CC;
            q = q > 0 ? q : 0;
            t |= (uint32_t)q << (4 * e);
        }
        t4[c] = t;
    }
    reinterpret_cast<uint4*>(tbl)[row * NNV + n4] =
        make_uint4(t4[0], t4[1], t4[2], t4[3]);

    // Sign bits: layout [row][w][n], one uint4 per w (components = chains).
    #pragma unroll
    for (int w = 0; w < 4; ++w)
        reinterpret_cast<uint4*>(bits_g)[(row * 4 + w) * NNV + n4] =
            make_uint4(bits[0][w], bits[1][w], bits[2][w], bits[3][w]);
}

// ---------------- Kernel C: compose prefix + emit z ----------------
__global__ __launch_bounds__(256) void refrac_emit(const uint32_t* __restrict__ tbl,
                                                   const uint32_t* __restrict__ bits_g,
                                                   float* __restrict__ z) {
    const int tid = threadIdx.x;
    const int pg = blockIdx.x >> 5;
    const int b  = blockIdx.x & 31;
    const int psub = tid >> 6;
    const int n4 = tid & 63;
    const int p = pg * PSUB + psub;
    const int pbase = pg * PSUB;

    __shared__ uint8_t ent_lds[PSUB][NN];

    // Each thread composes chain n = tid through tables 0..pbase+2,
    // recording entry states for this block's four chunks.
    {
        const int n = tid;
        uint32_t tv[PP];
        #pragma unroll
        for (int p2 = 0; p2 < PP; ++p2)
            tv[p2] = (p2 < pbase + PSUB - 1)
                         ? tbl[((size_t)b * PP + p2) * NN + n] : 0u;
        int e = 0;
        #pragma unroll
        for (int p2 = 0; p2 < PP; ++p2) {
            if (p2 >= pbase && p2 < pbase + PSUB)
                ent_lds[p2 - pbase][n] = (uint8_t)e;
            e = (int)((tv[p2] >> (4 * e)) & 0xFu);
        }
    }
    __syncthreads();

    // Load this chunk's sign bits (components = chains 4*n4+c).
    const size_t row = (size_t)b * PP + p;
    uint32_t bw[4][4];  // [w][c]
    #pragma unroll
    for (int w = 0; w < 4; ++w) {
        const uint4 bv =
            reinterpret_cast<const uint4*>(bits_g)[(row * 4 + w) * NNV + n4];
        bw[w][0] = bv.x; bw[w][1] = bv.y; bw[w][2] = bv.z; bw[w][3] = bv.w;
    }

    int ea[4];
    #pragma unroll
    for (int c = 0; c < 4; ++c) ea[c] = (int)ent_lds[psub][n4 * 4 + c];

    float4* __restrict__ zv = reinterpret_cast<float4*>(z)
        + ((size_t)b * TT + (size_t)p * CC) * NNV + n4;

    #pragma unroll
    for (int w = 0; w < 4; ++w) {
        for (int j2 = 0; j2 < 32; ++j2) {
            const int j = w * 32 + j2;
            float o[4];
            #pragma unroll
            for (int c = 0; c < 4; ++c) {
                const bool sp = (((bw[w][c] >> j2) & 1u) != 0u) & (j >= ea[c]);
                if (sp) ea[c] = j + 6;
                o[c] = sp ? 1.0f : 0.0f;
            }
            zv[(size_t)j * NNV] = make_float4(o[0], o[1], o[2], o[3]);
        }
    }
}

extern "C" void kernel_launch(void* const* d_in, const int* in_sizes, int n_in,
                              void* d_out, int out_size, void* d_ws, size_t ws_size,
                              hipStream_t stream) {
    const float* x = (const float*)d_in[0];
    float* z = (float*)d_out;

    // ws layout: tables (1 MiB) then packed sign bits (4 MiB).
    uint32_t* tbl = (uint32_t*)d_ws;
    uint32_t* bits_g = (uint32_t*)((char*)d_ws + (size_t)BB * PP * NN * sizeof(uint32_t));

    refrac_scan<<<dim3(BB * PG), 256, 0, stream>>>(x, tbl, bits_g);
    refrac_emit<<<dim3(BB * PG), 256, 0, stream>>>(tbl, bits_g, z);
}